// Round 8
// baseline (383.615 us; speedup 1.0000x reference)
//
#include <hip/hip_runtime.h>
#include <cmath>

// B=8, Cin=16, H=W=128, Cout=64, E=16, K=2
typedef __attribute__((ext_vector_type(8))) short bf16x8;   // MFMA A/B frag
typedef __attribute__((ext_vector_type(4))) float f32x4;    // MFMA C/D frag

static __device__ __forceinline__ unsigned int f2bf(float f) {
    union { float f; unsigned int u; } v; v.f = f;
    unsigned int r = v.u + 0x7FFFu + ((v.u >> 16) & 1u);   // round-to-nearest-even
    return r >> 16;
}

// ---- prep: ew [16][64][144] fp32 -> wb [e*64+cout][160] bf16 (B-frag rows, k-pad zeroed) ----
__global__ __launch_bounds__(256) void prep_w_kernel(const float* __restrict__ ew,
                                                     unsigned short* __restrict__ wb) {
    const int chunk = blockIdx.x * 256 + threadIdx.x;
    if (chunk >= 20480) return;                         // 1024 rows * 20 chunks
    const int rowid = chunk / 20;
    const int kc    = chunk - rowid * 20;
    uint4 dv = make_uint4(0u, 0u, 0u, 0u);
    if (kc < 18) {
        const float4 a = *(const float4*)(ew + rowid * 144 + kc * 8);
        const float4 c = *(const float4*)(ew + rowid * 144 + kc * 8 + 4);
        dv.x = f2bf(a.x) | (f2bf(a.y) << 16);
        dv.y = f2bf(a.z) | (f2bf(a.w) << 16);
        dv.z = f2bf(c.x) | (f2bf(c.y) << 16);
        dv.w = f2bf(c.z) | (f2bf(c.w) << 16);
    }
    *(uint4*)(wb + rowid * 160 + kc * 8) = dv;
}

// ---- main: dense per-expert GEMM, gate-weighted reg accumulation, zero atomics ----
// grid: 2048 = b(8) x row(128) x half(2); block: 256 thr = 4 waves (wave = n-frag)
// LDS (29952 B): Ab bf16[64][168] (21504, aliased by outt f32[64][65]=16640 after e-loop)
//                wexp f32[16][64] (4096) | lg f32[64][17] (4352)
__global__ __launch_bounds__(256, 4) void moe_dense_kernel(
    const float* __restrict__ x,              // [8][16][128][128]
    const float* __restrict__ gw,             // [16][16]
    const float* __restrict__ gb,             // [16]
    const unsigned short* __restrict__ wb,    // [1024][160] bf16
    const float* __restrict__ eb,             // [16][64]
    float* __restrict__ out,                  // [8][64][128][128]
    float* __restrict__ logits_out)           // [8][16][128][128]
{
    __shared__ __align__(16) char smem[29952];
    unsigned short* Ab   = (unsigned short*)smem;       // [64][168] bf16
    float*          wexp = (float*)(smem + 21504);      // [16][64]
    float*          lg   = (float*)(smem + 25600);      // [64][17]
    float*          outt = (float*)smem;                // [64][65] alias of Ab

    const int tid = threadIdx.x;
    const int b   = blockIdx.x >> 8;
    const int row = (blockIdx.x >> 1) & 127;
    const int px0 = (blockIdx.x & 1) << 6;

    const int lane = tid & 63;
    const int wave = tid >> 6;           // 0..3 = n-frag
    const int quad = lane >> 4;
    const int lq   = lane & 15;
    const int n    = lq + 16 * wave;     // this lane's cout

    // ---- phase 1 (no internal barriers): zero wexp, gate partials, im2col ----
    for (int i = tid; i < 1024; i += 256) wexp[i] = 0.f;

    {   // gate: thread (px, og) computes logits og*4..og*4+3 for pixel px
        const int px  = tid & 63;
        const int og  = tid >> 6;
        const int col = px0 + px;
        const float* xp = x + (b * 16) * 16384 + row * 128 + col;
        float xv[16];
        #pragma unroll
        for (int ci = 0; ci < 16; ++ci) xv[ci] = xp[ci * 16384];
        const int rbase = ((b * 16) * 128 + row) * 128 + col;
        #pragma unroll
        for (int j = 0; j < 4; ++j) {
            const int o = og * 4 + j;
            float acc = gb[o];
            #pragma unroll
            for (int i = 0; i < 16; ++i) acc += gw[o * 16 + i] * xv[i];
            lg[px * 17 + o] = acc;
            logits_out[rbase + o * 16384] = acc;
        }
    }

    {   // im2col A (bf16, stride 168 ushorts = 336 B): batched loads then convert
        const int px  = tid & 63;
        const int s0  = tid >> 6;        // 0..3
        const int col = px0 + px;
        float xa[36];
        #pragma unroll
        for (int j = 0; j < 12; ++j) {
            const int s  = s0 + 4 * j;   // 0..47 = ci*3+ky
            const int ci = s / 3;
            const int ky = s - ci * 3;
            int gr = row - 1 + ky;
            gr = gr < 0 ? 0 : (gr > 127 ? 127 : gr);
            const float* xr = x + ((b * 16 + ci) * 128 + gr) * 128;
            xa[3 * j + 0] = (col > 0)   ? xr[col - 1] : 0.f;
            xa[3 * j + 1] = xr[col];
            xa[3 * j + 2] = (col < 127) ? xr[col + 1] : 0.f;
        }
        #pragma unroll
        for (int j = 0; j < 12; ++j) {
            const int s  = s0 + 4 * j;
            const int ci = s / 3;
            const int ky = s - ci * 3;
            const int gr = row - 1 + ky;
            const bool ok = (gr >= 0) && (gr < 128);
            unsigned short* dst = Ab + px * 168 + ci * 9 + ky * 3;
            dst[0] = ok ? (unsigned short)f2bf(xa[3 * j + 0]) : (unsigned short)0;
            dst[1] = ok ? (unsigned short)f2bf(xa[3 * j + 1]) : (unsigned short)0;
            dst[2] = ok ? (unsigned short)f2bf(xa[3 * j + 2]) : (unsigned short)0;
        }
    }
    if (tid < 192) {                     // zero A k-pad 144..167 (3 x uint4 per row)
        const int px = tid / 3, h = tid - px * 3;
        *(uint4*)(Ab + px * 168 + 144 + h * 8) = make_uint4(0u, 0u, 0u, 0u);
    }
    __syncthreads();

    // ---- phase 2: top-2 routing (tid<64) + A register hoist (all threads) ----
    if (tid < 64) {
        float l[16];
        #pragma unroll
        for (int o = 0; o < 16; ++o) l[o] = lg[tid * 17 + o];
        float m = l[0];
        #pragma unroll
        for (int o = 1; o < 16; ++o) m = fmaxf(m, l[o]);
        float p0 = expf(l[0] - m), p1 = -1.f;
        int i0 = 0, i1 = 0;
        #pragma unroll
        for (int o = 1; o < 16; ++o) {
            float pv = expf(l[o] - m);
            if (pv > p0)      { p1 = p0; i1 = i0; p0 = pv; i0 = o; }
            else if (pv > p1) { p1 = pv; i1 = o; }
        }
        const float ws = p0 + p1;
        wexp[i0 * 64 + tid] = p0 / ws;
        wexp[i1 * 64 + tid] = p1 / ws;
    }
    bf16x8 af[4][5];
    #pragma unroll
    for (int mt = 0; mt < 4; ++mt) {
        const unsigned short* arow = Ab + (mt * 16 + lq) * 168 + quad * 8;
        #pragma unroll
        for (int ks = 0; ks < 5; ++ks) af[mt][ks] = *(const bf16x8*)(arow + ks * 32);
    }
    __syncthreads();                     // wexp ready; Ab fully hoisted (outt may alias now)

    // ---- phase 3: dense e-loop, B register-prefetched, weighted reg accumulation ----
    const unsigned short* bp = wb + n * 160 + quad * 8;
    bf16x8 bn[5];
    #pragma unroll
    for (int ks = 0; ks < 5; ++ks) bn[ks] = *(const bf16x8*)(bp + ks * 32);
    float bnb = eb[n];

    f32x4 facc[4] = {{0.f,0.f,0.f,0.f},{0.f,0.f,0.f,0.f},{0.f,0.f,0.f,0.f},{0.f,0.f,0.f,0.f}};

    for (int e = 0; e < 16; ++e) {
        bf16x8 bc[5];
        #pragma unroll
        for (int ks = 0; ks < 5; ++ks) bc[ks] = bn[ks];
        const float bias = bnb;
        if (e < 15) {                    // prefetch next expert (L2-hot, 320 KB table)
            const unsigned short* p = bp + (e + 1) * 10240;
            #pragma unroll
            for (int ks = 0; ks < 5; ++ks) bn[ks] = *(const bf16x8*)(p + ks * 32);
            bnb = eb[(e + 1) * 64 + n];
        }
        #pragma unroll
        for (int mt = 0; mt < 4; ++mt) {
            const f32x4 wv = *(const f32x4*)&wexp[e * 64 + mt * 16 + quad * 4];
            f32x4 acc = {0.f, 0.f, 0.f, 0.f};
            #pragma unroll
            for (int ks = 0; ks < 5; ++ks)
                acc = __builtin_amdgcn_mfma_f32_16x16x32_bf16(af[mt][ks], bc[ks], acc, 0, 0, 0);
            #pragma unroll
            for (int r = 0; r < 4; ++r)                 // C/D: row=quad*4+r, col=lq
                facc[mt][r] += wv[r] * (acc[r] + bias); // wv=0 for unrouted -> exact 0
        }
    }

    // ---- phase 4: transpose bounce (outt aliases Ab) + coalesced writeout ----
    #pragma unroll
    for (int mt = 0; mt < 4; ++mt)
        #pragma unroll
        for (int r = 0; r < 4; ++r)
            outt[(mt * 16 + quad * 4 + r) * 65 + n] = facc[mt][r];
    __syncthreads();
    for (int i = tid; i < 4096; i += 256) {
        const int c = i >> 6, px = i & 63;
        out[((b * 64 + c) * 128 + row) * 128 + px0 + px] = outt[px * 65 + c];
    }
}

extern "C" void kernel_launch(void* const* d_in, const int* in_sizes, int n_in,
                              void* d_out, int out_size, void* d_ws, size_t ws_size,
                              hipStream_t stream) {
    const float* x  = (const float*)d_in[0];
    const float* gw = (const float*)d_in[1];
    const float* gb = (const float*)d_in[2];
    const float* ew = (const float*)d_in[3];
    const float* eb = (const float*)d_in[4];
    float* out        = (float*)d_out;
    float* logits_out = out + 8 * 64 * 128 * 128;
    unsigned short* wb = (unsigned short*)d_ws;      // 1024*160*2 = 327,680 B

    prep_w_kernel<<<dim3(80), dim3(256), 0, stream>>>(ew, wb);
    moe_dense_kernel<<<dim3(2048), dim3(256), 0, stream>>>(
        x, gw, gb, wb, eb, out, logits_out);
}

// Round 10
// 132.381 us; speedup vs baseline: 2.8978x; 2.8978x over previous
//
#include <hip/hip_runtime.h>
#include <cmath>

// B=8, Cin=16, H=W=128, Cout=64, E=16, K=2
typedef __attribute__((ext_vector_type(8))) short bf16x8;   // MFMA A/B frag
typedef __attribute__((ext_vector_type(4))) float f32x4;    // MFMA C/D frag

static __device__ __forceinline__ unsigned int f2bf(float f) {
    union { float f; unsigned int u; } v; v.f = f;
    unsigned int r = v.u + 0x7FFFu + ((v.u >> 16) & 1u);   // round-to-nearest-even
    return r >> 16;
}

// ---- prep: ew [16][64][144] fp32 -> wb [e*64+cout][160] bf16 ----
// k 0..143 = weights, k 144 = bias (pairs with A's 1.0 column), k 145..159 = 0
__global__ __launch_bounds__(256) void prep_w_kernel(const float* __restrict__ ew,
                                                     const float* __restrict__ eb,
                                                     unsigned short* __restrict__ wb) {
    const int chunk = blockIdx.x * 256 + threadIdx.x;
    if (chunk >= 20480) return;                         // 1024 rows * 20 chunks
    const int rowid = chunk / 20;
    const int kc    = chunk - rowid * 20;
    uint4 dv = make_uint4(0u, 0u, 0u, 0u);
    if (kc < 18) {
        const float4 a = *(const float4*)(ew + rowid * 144 + kc * 8);
        const float4 c = *(const float4*)(ew + rowid * 144 + kc * 8 + 4);
        dv.x = f2bf(a.x) | (f2bf(a.y) << 16);
        dv.y = f2bf(a.z) | (f2bf(a.w) << 16);
        dv.z = f2bf(c.x) | (f2bf(c.y) << 16);
        dv.w = f2bf(c.z) | (f2bf(c.w) << 16);
    } else if (kc == 18) {
        dv.x = f2bf(eb[rowid]);                         // k=144 -> bias
    }
    *(uint4*)(wb + rowid * 160 + kc * 8) = dv;
}

// ---- main: dense per-expert GEMM, gate-weighted reg accumulation, zero atomics ----
// grid: 2048 = b(8) x row(128) x half(2); block: 256 thr = 4 waves (wave = n-frag)
__global__ __launch_bounds__(256, 3) void moe_dense_kernel(
    const float* __restrict__ x,              // [8][16][128][128]
    const float* __restrict__ gw,             // [16][16]
    const float* __restrict__ gb,             // [16]
    const unsigned short* __restrict__ wb,    // [1024][160] bf16 (weights + bias col)
    float* __restrict__ out,                  // [8][64][128][128]
    float* __restrict__ logits_out)           // [8][16][128][128]
{
    __shared__ __align__(16) unsigned short Ab[64 * 168];   // im2col bf16, stride 336 B
    __shared__ __align__(16) float wexp[16 * 64];           // [e][px] gate weight (0 if unrouted)
    __shared__ float lg[64 * 17];                           // gate logit staging
    __shared__ float outt[64 * 65];                         // transpose bounce (separate: no alias!)

    const int tid = threadIdx.x;
    const int b   = blockIdx.x >> 8;
    const int row = (blockIdx.x >> 1) & 127;
    const int px0 = (blockIdx.x & 1) << 6;

    const int lane = tid & 63;
    const int wave = tid >> 6;           // 0..3 = n-frag
    const int quad = lane >> 4;
    const int lq   = lane & 15;
    const int n    = lq + 16 * wave;     // this lane's cout

    // ---- phase 1 (no internal barriers): zero wexp, gate partials, im2col ----
    for (int i = tid; i < 1024; i += 256) wexp[i] = 0.f;

    {   // gate: thread (px, og) computes logits og*4..og*4+3 for pixel px
        const int px  = tid & 63;
        const int og  = tid >> 6;
        const int col = px0 + px;
        const float* xp = x + (b * 16) * 16384 + row * 128 + col;
        float xv[16];
        #pragma unroll
        for (int ci = 0; ci < 16; ++ci) xv[ci] = xp[ci * 16384];
        const int rbase = ((b * 16) * 128 + row) * 128 + col;
        #pragma unroll
        for (int j = 0; j < 4; ++j) {
            const int o = og * 4 + j;
            float acc = gb[o];
            #pragma unroll
            for (int i = 0; i < 16; ++i) acc += gw[o * 16 + i] * xv[i];
            lg[px * 17 + o] = acc;
            logits_out[rbase + o * 16384] = acc;
        }
    }

    {   // im2col A (bf16, stride 168 ushorts = 336 B): batched loads then convert
        const int px  = tid & 63;
        const int s0  = tid >> 6;        // 0..3
        const int col = px0 + px;
        float xa[36];
        #pragma unroll
        for (int j = 0; j < 12; ++j) {
            const int s  = s0 + 4 * j;   // 0..47 = ci*3+ky
            const int ci = s / 3;
            const int ky = s - ci * 3;
            int gr = row - 1 + ky;
            gr = gr < 0 ? 0 : (gr > 127 ? 127 : gr);
            const float* xr = x + ((b * 16 + ci) * 128 + gr) * 128;
            xa[3 * j + 0] = (col > 0)   ? xr[col - 1] : 0.f;
            xa[3 * j + 1] = xr[col];
            xa[3 * j + 2] = (col < 127) ? xr[col + 1] : 0.f;
        }
        #pragma unroll
        for (int j = 0; j < 12; ++j) {
            const int s  = s0 + 4 * j;
            const int ci = s / 3;
            const int ky = s - ci * 3;
            const int gr = row - 1 + ky;
            const bool ok = (gr >= 0) && (gr < 128);
            unsigned short* dst = Ab + px * 168 + ci * 9 + ky * 3;
            dst[0] = ok ? (unsigned short)f2bf(xa[3 * j + 0]) : (unsigned short)0;
            dst[1] = ok ? (unsigned short)f2bf(xa[3 * j + 1]) : (unsigned short)0;
            dst[2] = ok ? (unsigned short)f2bf(xa[3 * j + 2]) : (unsigned short)0;
        }
    }
    if (tid < 192) {                     // A k-pad: k144 = 1.0 (bias column), 145..167 = 0
        const int px = tid / 3, h = tid - px * 3;
        uint4 pv = make_uint4(h == 0 ? 0x00003F80u : 0u, 0u, 0u, 0u);
        *(uint4*)(Ab + px * 168 + 144 + h * 8) = pv;
    }
    __syncthreads();

    // ---- phase 2: top-2 routing (tid<64) ----
    if (tid < 64) {
        float l[16];
        #pragma unroll
        for (int o = 0; o < 16; ++o) l[o] = lg[tid * 17 + o];
        float m = l[0];
        #pragma unroll
        for (int o = 1; o < 16; ++o) m = fmaxf(m, l[o]);
        float p0 = expf(l[0] - m), p1 = -1.f;
        int i0 = 0, i1 = 0;
        #pragma unroll
        for (int o = 1; o < 16; ++o) {
            float pv = expf(l[o] - m);
            if (pv > p0)      { p1 = p0; i1 = i0; p0 = pv; i0 = o; }
            else if (pv > p1) { p1 = pv; i1 = o; }
        }
        const float ws = p0 + p1;
        wexp[i0 * 64 + tid] = p0 / ws;
        wexp[i1 * 64 + tid] = p1 / ws;
    }
    // A fragments (compiler may keep in regs or reload from LDS — R7-verified no spills)
    bf16x8 af[4][5];
    #pragma unroll
    for (int mt = 0; mt < 4; ++mt) {
        const unsigned short* arow = Ab + (mt * 16 + lq) * 168 + quad * 8;
        #pragma unroll
        for (int ks = 0; ks < 5; ++ks) af[mt][ks] = *(const bf16x8*)(arow + ks * 32);
    }
    __syncthreads();                     // wexp ready

    // ---- phase 3: dense e-loop, B register-prefetched, weighted reg accumulation ----
    const unsigned short* bp = wb + n * 160 + quad * 8;
    bf16x8 bn[5];
    #pragma unroll
    for (int ks = 0; ks < 5; ++ks) bn[ks] = *(const bf16x8*)(bp + ks * 32);

    f32x4 facc[4] = {{0.f,0.f,0.f,0.f},{0.f,0.f,0.f,0.f},{0.f,0.f,0.f,0.f},{0.f,0.f,0.f,0.f}};

    for (int e = 0; e < 16; ++e) {
        bf16x8 bc[5];
        #pragma unroll
        for (int ks = 0; ks < 5; ++ks) bc[ks] = bn[ks];
        if (e < 15) {                    // prefetch next expert (L2-hot, 320 KB table)
            const unsigned short* p = bp + (e + 1) * 10240;
            #pragma unroll
            for (int ks = 0; ks < 5; ++ks) bn[ks] = *(const bf16x8*)(p + ks * 32);
        }
        #pragma unroll
        for (int mt = 0; mt < 4; ++mt) {
            const f32x4 wv = *(const f32x4*)&wexp[e * 64 + mt * 16 + quad * 4];
            f32x4 acc = {0.f, 0.f, 0.f, 0.f};
            #pragma unroll
            for (int ks = 0; ks < 5; ++ks)
                acc = __builtin_amdgcn_mfma_f32_16x16x32_bf16(af[mt][ks], bc[ks], acc, 0, 0, 0);
            // acc already includes this expert's bias (A k144=1.0 x B k144=bias)
            #pragma unroll
            for (int r = 0; r < 4; ++r)             // C/D: row=quad*4+r, col=lq
                facc[mt][r] += wv[r] * acc[r];
        }
    }

    // ---- phase 4: transpose bounce + coalesced writeout ----
    #pragma unroll
    for (int mt = 0; mt < 4; ++mt)
        #pragma unroll
        for (int r = 0; r < 4; ++r)
            outt[(mt * 16 + quad * 4 + r) * 65 + n] = facc[mt][r];
    __syncthreads();
    for (int i = tid; i < 4096; i += 256) {
        const int c = i >> 6, px = i & 63;
        out[((b * 64 + c) * 128 + row) * 128 + px0 + px] = outt[px * 65 + c];
    }
}

extern "C" void kernel_launch(void* const* d_in, const int* in_sizes, int n_in,
                              void* d_out, int out_size, void* d_ws, size_t ws_size,
                              hipStream_t stream) {
    const float* x  = (const float*)d_in[0];
    const float* gw = (const float*)d_in[1];
    const float* gb = (const float*)d_in[2];
    const float* ew = (const float*)d_in[3];
    const float* eb = (const float*)d_in[4];
    float* out        = (float*)d_out;
    float* logits_out = out + 8 * 64 * 128 * 128;
    unsigned short* wb = (unsigned short*)d_ws;      // 1024*160*2 = 327,680 B

    prep_w_kernel<<<dim3(80), dim3(256), 0, stream>>>(ew, eb, wb);
    moe_dense_kernel<<<dim3(2048), dim3(256), 0, stream>>>(
        x, gw, gb, wb, out, logits_out);
}

// Round 11
// 121.064 us; speedup vs baseline: 3.1687x; 1.0935x over previous
//
#include <hip/hip_runtime.h>
#include <cmath>

// B=8, Cin=16, H=W=128, Cout=64, E=16, K=2
typedef __attribute__((ext_vector_type(8))) short bf16x8;   // MFMA A/B frag
typedef __attribute__((ext_vector_type(4))) float f32x4;    // MFMA C/D frag

static __device__ __forceinline__ unsigned int f2bf(float f) {
    union { float f; unsigned int u; } v; v.f = f;
    unsigned int r = v.u + 0x7FFFu + ((v.u >> 16) & 1u);   // round-to-nearest-even
    return r >> 16;
}

// ---- prep: ew [16][64][144] fp32 + eb -> wb chunks [e][ks][nf][quad][lq] x 8 bf16 ----
// Wave-contiguous: lane (quad*16+lq) of wave nf reads chunk (e,ks,nf,quad,lq) ->
// 64 lanes x 16 B = 1 KB contiguous per load instruction.
// k = ks*32 + quad*8; k==144 holds bias (pairs with A's 1.0 column), k>144 zero.
__global__ __launch_bounds__(256) void prep_w_kernel(const float* __restrict__ ew,
                                                     const float* __restrict__ eb,
                                                     unsigned short* __restrict__ wb) {
    const int c = blockIdx.x * 256 + threadIdx.x;
    if (c >= 20480) return;                     // 16 e * 1280 chunks
    const int e    = c / 1280;
    const int r    = c - e * 1280;
    const int ks   = r >> 8;                    // 0..4
    const int nf   = (r >> 6) & 3;
    const int quad = (r >> 4) & 3;
    const int lq   = r & 15;
    const int n    = nf * 16 + lq;
    const int k0   = ks * 32 + quad * 8;
    uint4 dv = make_uint4(0u, 0u, 0u, 0u);
    if (k0 <= 136) {                            // full 8-wide weight chunk
        const float* s = ew + (e * 64 + n) * 144 + k0;
        const float4 a  = *(const float4*)(s);
        const float4 cc = *(const float4*)(s + 4);
        dv.x = f2bf(a.x)  | (f2bf(a.y)  << 16);
        dv.y = f2bf(a.z)  | (f2bf(a.w)  << 16);
        dv.z = f2bf(cc.x) | (f2bf(cc.y) << 16);
        dv.w = f2bf(cc.z) | (f2bf(cc.w) << 16);
    } else if (k0 == 144) {
        dv.x = f2bf(eb[e * 64 + n]);            // bias column
    }
    *(uint4*)(wb + c * 8) = dv;
}

// ---- main: dense per-expert GEMM, gate-weighted reg accumulation, zero atomics ----
// grid: 2048 = b(8) x row(128) x half(2); block: 256 thr = 4 waves (wave = n-frag)
__global__ __launch_bounds__(256, 2) void moe_dense_kernel(
    const float* __restrict__ x,              // [8][16][128][128]
    const float* __restrict__ gw,             // [16][16]
    const float* __restrict__ gb,             // [16]
    const unsigned short* __restrict__ wb,    // [20480 chunks] bf16 (see prep)
    float* __restrict__ out,                  // [8][64][128][128]
    float* __restrict__ logits_out)           // [8][16][128][128]
{
    __shared__ __align__(16) unsigned short Ab[64 * 168];   // im2col bf16, stride 336 B
    __shared__ __align__(16) float wexp[16 * 64];           // [e][px] gate weight (0 if unrouted)
    __shared__ float lg[64 * 17];                           // gate logit staging
    __shared__ float outt[64 * 65];                         // transpose bounce (no aliasing!)

    const int tid = threadIdx.x;
    const int b   = blockIdx.x >> 8;
    const int row = (blockIdx.x >> 1) & 127;
    const int px0 = (blockIdx.x & 1) << 6;

    const int lane = tid & 63;
    const int wave = tid >> 6;           // 0..3 = n-frag
    const int quad = lane >> 4;
    const int lq   = lane & 15;
    const int n    = lq + 16 * wave;     // this lane's cout

    // ---- phase 1 (no internal barriers): zero wexp, gate partials, im2col ----
    for (int i = tid; i < 1024; i += 256) wexp[i] = 0.f;

    {   // gate: thread (px, og) computes logits og*4..og*4+3 for pixel px
        const int px  = tid & 63;
        const int og  = tid >> 6;
        const int col = px0 + px;
        const float* xp = x + (b * 16) * 16384 + row * 128 + col;
        float xv[16];
        #pragma unroll
        for (int ci = 0; ci < 16; ++ci) xv[ci] = xp[ci * 16384];
        const int rbase = ((b * 16) * 128 + row) * 128 + col;
        #pragma unroll
        for (int j = 0; j < 4; ++j) {
            const int o = og * 4 + j;
            float acc = gb[o];
            #pragma unroll
            for (int i = 0; i < 16; ++i) acc += gw[o * 16 + i] * xv[i];
            lg[px * 17 + o] = acc;
            logits_out[rbase + o * 16384] = acc;
        }
    }

    {   // im2col A (bf16, stride 168 ushorts = 336 B): batched loads then convert
        const int px  = tid & 63;
        const int s0  = tid >> 6;        // 0..3
        const int col = px0 + px;
        float xa[36];
        #pragma unroll
        for (int j = 0; j < 12; ++j) {
            const int s  = s0 + 4 * j;   // 0..47 = ci*3+ky
            const int ci = s / 3;
            const int ky = s - ci * 3;
            int gr = row - 1 + ky;
            gr = gr < 0 ? 0 : (gr > 127 ? 127 : gr);
            const float* xr = x + ((b * 16 + ci) * 128 + gr) * 128;
            xa[3 * j + 0] = (col > 0)   ? xr[col - 1] : 0.f;
            xa[3 * j + 1] = xr[col];
            xa[3 * j + 2] = (col < 127) ? xr[col + 1] : 0.f;
        }
        #pragma unroll
        for (int j = 0; j < 12; ++j) {
            const int s  = s0 + 4 * j;
            const int ci = s / 3;
            const int ky = s - ci * 3;
            const int gr = row - 1 + ky;
            const bool ok = (gr >= 0) && (gr < 128);
            unsigned short* dst = Ab + px * 168 + ci * 9 + ky * 3;
            dst[0] = ok ? (unsigned short)f2bf(xa[3 * j + 0]) : (unsigned short)0;
            dst[1] = ok ? (unsigned short)f2bf(xa[3 * j + 1]) : (unsigned short)0;
            dst[2] = ok ? (unsigned short)f2bf(xa[3 * j + 2]) : (unsigned short)0;
        }
    }
    if (tid < 192) {                     // A k-pad: k144 = 1.0 (bias column), 145..167 = 0
        const int px = tid / 3, h = tid - px * 3;
        uint4 pv = make_uint4(h == 0 ? 0x00003F80u : 0u, 0u, 0u, 0u);
        *(uint4*)(Ab + px * 168 + 144 + h * 8) = pv;
    }
    __syncthreads();

    // ---- phase 2: top-2 routing (tid<64) ----
    if (tid < 64) {
        float l[16];
        #pragma unroll
        for (int o = 0; o < 16; ++o) l[o] = lg[tid * 17 + o];
        float m = l[0];
        #pragma unroll
        for (int o = 1; o < 16; ++o) m = fmaxf(m, l[o]);
        float p0 = expf(l[0] - m), p1 = -1.f;
        int i0 = 0, i1 = 0;
        #pragma unroll
        for (int o = 1; o < 16; ++o) {
            float pv = expf(l[o] - m);
            if (pv > p0)      { p1 = p0; i1 = i0; p0 = pv; i0 = o; }
            else if (pv > p1) { p1 = pv; i1 = o; }
        }
        const float ws = p0 + p1;
        wexp[i0 * 64 + tid] = p0 / ws;
        wexp[i1 * 64 + tid] = p1 / ws;
    }
    // A fragments: load once and PIN in VGPRs (opaque asm blocks LDS rematerialization)
    bf16x8 af[4][5];
    #pragma unroll
    for (int mt = 0; mt < 4; ++mt) {
        const unsigned short* arow = Ab + (mt * 16 + lq) * 168 + quad * 8;
        #pragma unroll
        for (int ks = 0; ks < 5; ++ks) af[mt][ks] = *(const bf16x8*)(arow + ks * 32);
    }
    #pragma unroll
    for (int mt = 0; mt < 4; ++mt)
        #pragma unroll
        for (int ks = 0; ks < 5; ++ks)
            asm volatile("" : "+v"(af[mt][ks]));
    __syncthreads();                     // wexp ready

    // ---- phase 3: dense e-loop; B loads wave-contiguous (1 KB/instr), reg prefetch ----
    const unsigned short* bp = wb + wave * 512 + lane * 8;   // chunk (e,ks,nf=wave,quad,lq)
    bf16x8 bn[5];
    #pragma unroll
    for (int ks = 0; ks < 5; ++ks) bn[ks] = *(const bf16x8*)(bp + ks * 2048);

    f32x4 facc[4] = {{0.f,0.f,0.f,0.f},{0.f,0.f,0.f,0.f},{0.f,0.f,0.f,0.f},{0.f,0.f,0.f,0.f}};

    for (int e = 0; e < 16; ++e) {
        bf16x8 bc[5];
        #pragma unroll
        for (int ks = 0; ks < 5; ++ks) bc[ks] = bn[ks];
        if (e < 15) {                    // prefetch next expert (contiguous, L2-hot)
            const unsigned short* p = bp + (e + 1) * 10240;
            #pragma unroll
            for (int ks = 0; ks < 5; ++ks) bn[ks] = *(const bf16x8*)(p + ks * 2048);
        }
        #pragma unroll
        for (int mt = 0; mt < 4; ++mt) {
            const f32x4 wv = *(const f32x4*)&wexp[e * 64 + mt * 16 + quad * 4];
            f32x4 acc = {0.f, 0.f, 0.f, 0.f};
            #pragma unroll
            for (int ks = 0; ks < 5; ++ks)
                acc = __builtin_amdgcn_mfma_f32_16x16x32_bf16(af[mt][ks], bc[ks], acc, 0, 0, 0);
            // acc already includes this expert's bias (A k144=1.0 x B k144=bias)
            #pragma unroll
            for (int r = 0; r < 4; ++r)             // C/D: row=quad*4+r, col=lq
                facc[mt][r] += wv[r] * acc[r];
        }
    }

    // ---- phase 4: transpose bounce + coalesced writeout ----
    #pragma unroll
    for (int mt = 0; mt < 4; ++mt)
        #pragma unroll
        for (int r = 0; r < 4; ++r)
            outt[(mt * 16 + quad * 4 + r) * 65 + n] = facc[mt][r];
    __syncthreads();
    for (int i = tid; i < 4096; i += 256) {
        const int c = i >> 6, px = i & 63;
        out[((b * 64 + c) * 128 + row) * 128 + px0 + px] = outt[px * 65 + c];
    }
}

extern "C" void kernel_launch(void* const* d_in, const int* in_sizes, int n_in,
                              void* d_out, int out_size, void* d_ws, size_t ws_size,
                              hipStream_t stream) {
    const float* x  = (const float*)d_in[0];
    const float* gw = (const float*)d_in[1];
    const float* gb = (const float*)d_in[2];
    const float* ew = (const float*)d_in[3];
    const float* eb = (const float*)d_in[4];
    float* out        = (float*)d_out;
    float* logits_out = out + 8 * 64 * 128 * 128;
    unsigned short* wb = (unsigned short*)d_ws;      // 20480 chunks * 16 B = 327,680 B

    prep_w_kernel<<<dim3(80), dim3(256), 0, stream>>>(ew, eb, wb);
    moe_dense_kernel<<<dim3(2048), dim3(256), 0, stream>>>(
        x, gw, gb, wb, out, logits_out);
}